// Round 2
// baseline (517.351 us; speedup 1.0000x reference)
//
#include <hip/hip_runtime.h>
#include <hip/hip_fp16.h>
#include <hip/hip_cooperative_groups.h>

namespace cg = cooperative_groups;

// ---------------------------------------------------------------------------
// VGAE encoder, gather-form, fp16 gather table.
//   a[i] = dis_i*(g[i] + sum_{e:dst=i} g[src_e]),  g = fp16(dis (.) h)
// R13: the three fused layer dispatches merged into ONE cooperative kernel
//   (grid.sync between layers). 6 -> 4 dispatches. Atomic tile dispenser
//   (tctr[3] in ws, zeroed by the memset) avoids the 2-vs-1 static-stride
//   imbalance at coop grid = 4 blocks/CU. Discriminator round: if dur drops
//   ~25-35 us, dispatch/drain overhead was the residual -> merge preprocess
//   next; if flat, kernels themselves are slow -> split back + attack
//   bucket/finalize. k_layers now exceeds the fill kernels' 43 us so top-5
//   will finally show its counters.
//   NT loads ONLY on read-once streams (src/dst). NT stores banned (R10).
// ---------------------------------------------------------------------------

#define BK_BITS 9
#define BK      (1 << BK_BITS)     // 512 dst nodes per bucket
#define BMASK   (BK - 1)
#define EPT     16
#define CHUNK   (256 * EPT)        // 4096 edges per block
#define CAP     16384              // bucket capacity (mean 8192, max ~8.6k)

typedef int   vint4   __attribute__((ext_vector_type(4)));
typedef uint  vuint4  __attribute__((ext_vector_type(4)));
typedef float vfloat4 __attribute__((ext_vector_type(4)));

#define NTL(p) __builtin_nontemporal_load(p)

// ---- pass A: scatter edges into capacity-padded dst-buckets ----------------
__global__ void k_bucket(const int* __restrict__ src, const int* __restrict__ dst,
                         int* __restrict__ bcur, int* __restrict__ ebuf, int E) {
    __shared__ int lcnt[256];
    __shared__ int lbase[256];
    int t = threadIdx.x;
    lcnt[t] = 0;
    __syncthreads();
    int e0 = blockIdx.x * CHUNK;
    int pk[EPT];
#pragma unroll
    for (int i = 0; i < EPT; ++i) {
        int e = e0 + i * 256 + t;
        pk[i] = -1;
        if (e < E) {
            int d = NTL(dst + e);
            int b = d >> BK_BITS;
            int off = atomicAdd(&lcnt[b], 1);          // off < CHUNK = 4096
            pk[i] = (b << 21) | (off << BK_BITS) | (d & BMASK);
        }
    }
    __syncthreads();
    lbase[t] = t * CAP + atomicAdd(&bcur[t], lcnt[t]);
    __syncthreads();
#pragma unroll
    for (int i = 0; i < EPT; ++i) {
        int e = e0 + i * 256 + t;
        if (e < E) {
            int b   = pk[i] >> 21;
            int off = (pk[i] >> BK_BITS) & 4095;
            int dl  = pk[i] & BMASK;
            int pos = lbase[b] + off;
            if (pos < (b + 1) * CAP)                  // overflow guard (never hit)
                ebuf[pos] = (NTL(src + e) << BK_BITS) | dl;
        }
    }
}

// ---- pass B: per-bucket finalize: starts, dis, sorted src, g0 --------------
__global__ void k_finalize(const int* __restrict__ bcur, int* __restrict__ starts,
                           float* __restrict__ dis, const int* __restrict__ ebuf,
                           int* __restrict__ es, const float* __restrict__ x,
                           __half* __restrict__ g0, int n, int E) {
    __shared__ int   hist[BK];
    __shared__ int   sc[BK];
    __shared__ int   sb[256];
    __shared__ float disL[BK];
    int b = blockIdx.x, t = threadIdx.x;
    if (t < 256) sb[t] = min(bcur[t], CAP);
    hist[t] = 0;
    __syncthreads();
    for (int o = 1; o < 256; o <<= 1) {
        int xv = 0;
        if (t < 256 && t >= o) xv = sb[t - o];
        __syncthreads();
        if (t < 256) sb[t] += xv;
        __syncthreads();
    }
    int cnt = min(bcur[b], CAP);
    int beg = sb[b] - cnt;                  // exclusive scan at b
    const int* eb = ebuf + (size_t)b * CAP;
    for (int j = t; j < cnt; j += BK)
        atomicAdd(&hist[eb[j] & BMASK], 1);
    __syncthreads();
    int cv = hist[t];
    sc[t] = cv;
    __syncthreads();
    for (int o = 1; o < BK; o <<= 1) {
        int xv = (t >= o) ? sc[t - o] : 0;
        __syncthreads();
        sc[t] += xv;
        __syncthreads();
    }
    int excl = sc[t] - cv;
    int gnode = (b << BK_BITS) + t;
    float dv = rsqrtf((float)cv + 1.0f);    // +1 = self loop
    disL[t] = dv;
    if (gnode < n) {
        starts[gnode] = beg + excl;
        dis[gnode] = dv;
    }
    if (b == 0 && t == 0) starts[n] = E;
    hist[t] = excl;                         // reuse as cursor
    __syncthreads();
    for (int j = t; j < cnt; j += BK) {
        int v = eb[j];
        int off = atomicAdd(&hist[v & BMASK], 1);
        es[beg + off] = v >> BK_BITS;       // normal store: L2 combines
    }
    // g0 = fp16(dis (.) x) for this bucket's nodes (coalesced 8 B stores)
    int node0 = b << BK_BITS;
    const float4* x4 = (const float4*)x;
    uint2* g2 = (uint2*)g0;
    for (int idx = t; idx < BK * 8; idx += BK) {
        int r = idx >> 3, lane = idx & 7;
        int nd = node0 + r;
        if (nd < n) {
            float d = disL[r];
            float4 v = x4[(size_t)nd * 8 + lane];
            __half2 lo = __floats2half2_rn(d * v.x, d * v.y);
            __half2 hi = __floats2half2_rn(d * v.z, d * v.w);
            uint2 u;
            u.x = *(unsigned int*)&lo;
            u.y = *(unsigned int*)&hi;
            g2[(size_t)nd * 8 + lane] = u;
        }
    }
}

// ---- gather helper: accumulate 8 halves into fp32 --------------------------
__device__ inline void acc8(uint4 u, float* s) {
    __half2 h0 = *(__half2*)&u.x, h1 = *(__half2*)&u.y;
    __half2 h2 = *(__half2*)&u.z, h3 = *(__half2*)&u.w;
    float2 f0 = __half22float2(h0), f1 = __half22float2(h1);
    float2 f2 = __half22float2(h2), f3 = __half22float2(h3);
    s[0] += f0.x; s[1] += f0.y; s[2] += f1.x; s[3] += f1.y;
    s[4] += f2.x; s[5] += f2.y; s[6] += f3.x; s[7] += f3.y;
}

// ---- gather core: s[8] = self + sum over edge list (fp32 accum) ------------
__device__ inline void gather32(const int* __restrict__ starts,
                                const int* __restrict__ es,
                                const uint4* __restrict__ g4,
                                int node, int lane, float* s) {
    acc8(g4[(size_t)node * 4 + lane], s);  // self term
    int j = starts[node], end = starts[node + 1];
    while (j < end && (j & 3)) {           // align to int4 boundary
        acc8(g4[(size_t)es[j] * 4 + lane], s);
        ++j;
    }
    for (; j + 8 <= end; j += 8) {         // 8 gathers in flight
        int4 e0 = *(const int4*)(es + j);
        int4 e1 = *(const int4*)(es + j + 4);
        uint4 u0 = g4[(size_t)e0.x * 4 + lane];
        uint4 u1 = g4[(size_t)e0.y * 4 + lane];
        uint4 u2 = g4[(size_t)e0.z * 4 + lane];
        uint4 u3 = g4[(size_t)e0.w * 4 + lane];
        uint4 u4 = g4[(size_t)e1.x * 4 + lane];
        uint4 u5 = g4[(size_t)e1.y * 4 + lane];
        uint4 u6 = g4[(size_t)e1.z * 4 + lane];
        uint4 u7 = g4[(size_t)e1.w * 4 + lane];
        acc8(u0, s); acc8(u1, s); acc8(u2, s); acc8(u3, s);
        acc8(u4, s); acc8(u5, s); acc8(u6, s); acc8(u7, s);
    }
    if (j + 4 <= end) {
        int4 e0 = *(const int4*)(es + j);
        uint4 u0 = g4[(size_t)e0.x * 4 + lane];
        uint4 u1 = g4[(size_t)e0.y * 4 + lane];
        uint4 u2 = g4[(size_t)e0.z * 4 + lane];
        uint4 u3 = g4[(size_t)e0.w * 4 + lane];
        acc8(u0, s); acc8(u1, s); acc8(u2, s); acc8(u3, s);
        j += 4;
    }
    for (; j < end; ++j) acc8(g4[(size_t)es[j] * 4 + lane], s);
}

// ---- hidden-layer phase: gout = fp16(dis (.) relu(agg(g) @ W + b)) ---------
// 64 nodes/tile, 4 lanes/node; tiles from an atomic dispenser (tctr).
__device__ __forceinline__ void hidden_phase(
        const int* __restrict__ starts, const int* __restrict__ es,
        const float* __restrict__ dis, const __half* __restrict__ g,
        const float* __restrict__ W, const float* __restrict__ bias,
        __half* __restrict__ gout, int n, int ntiles, int* __restrict__ tctr,
        float (*Ws)[66], float (*Xs)[33], int* tileShared) {
    int t = threadIdx.x;
    for (int i = t; i < 1024; i += 256) Ws[i >> 5][i & 31] = W[i];
    int r = t >> 2, lane = t & 3, c0 = lane * 8;
    float bc[8];
#pragma unroll
    for (int i = 0; i < 8; ++i) bc[i] = bias[c0 + i];
    for (;;) {
        if (t == 0) *tileShared = atomicAdd(tctr, 1);
        __syncthreads();                   // publish tile; prev-tile GEMM done
        int tile = *tileShared;
        if (tile >= ntiles) break;         // uniform across block
        int node = tile * 64 + r;
        bool alive = node < n;
        float dd = 0.f;
        float s[8] = {0, 0, 0, 0, 0, 0, 0, 0};
        if (alive) {
            gather32(starts, es, (const uint4*)g, node, lane, s);
            dd = dis[node];
#pragma unroll
            for (int i = 0; i < 8; ++i) Xs[r][c0 + i] = dd * s[i];
        }
        __syncthreads();                   // Xs (and Ws, first iter) visible
        if (alive) {
            float acc[8];
#pragma unroll
            for (int i = 0; i < 8; ++i) acc[i] = bc[i];
#pragma unroll 8
            for (int k = 0; k < 32; ++k) {
                float xv = Xs[r][k];
#pragma unroll
                for (int i = 0; i < 8; ++i) acc[i] += xv * Ws[k][c0 + i];
            }
            __half2 h0 = __floats2half2_rn(dd * fmaxf(acc[0], 0.f), dd * fmaxf(acc[1], 0.f));
            __half2 h1 = __floats2half2_rn(dd * fmaxf(acc[2], 0.f), dd * fmaxf(acc[3], 0.f));
            __half2 h2 = __floats2half2_rn(dd * fmaxf(acc[4], 0.f), dd * fmaxf(acc[5], 0.f));
            __half2 h3 = __floats2half2_rn(dd * fmaxf(acc[6], 0.f), dd * fmaxf(acc[7], 0.f));
            uint4 u;
            u.x = *(unsigned int*)&h0; u.y = *(unsigned int*)&h1;
            u.z = *(unsigned int*)&h2; u.w = *(unsigned int*)&h3;
            ((uint4*)gout)[(size_t)node * 4 + lane] = u;
        }
    }
}

// ---- output phase: out = [agg(g) @ Wmu + bmu | agg(g) @ Wlv + blv] ---------
__device__ __forceinline__ void final_phase(
        const int* __restrict__ starts, const int* __restrict__ es,
        const float* __restrict__ dis, const __half* __restrict__ g,
        const float* __restrict__ Wmu, const float* __restrict__ Wlv,
        const float* __restrict__ bmu, const float* __restrict__ blv,
        float* __restrict__ out, int n, int ntiles, int* __restrict__ tctr,
        float (*Ws)[66], float (*Xs)[33], int* tileShared) {
    int t = threadIdx.x;
    for (int i = t; i < 1024; i += 256) {
        Ws[i >> 5][i & 31]        = Wmu[i];
        Ws[i >> 5][32 + (i & 31)] = Wlv[i];
    }
    int r = t >> 2, lane = t & 3, c0 = lane * 8;
    float bm[8], bl[8];
#pragma unroll
    for (int i = 0; i < 8; ++i) { bm[i] = bmu[c0 + i]; bl[i] = blv[c0 + i]; }
    for (;;) {
        if (t == 0) *tileShared = atomicAdd(tctr, 1);
        __syncthreads();
        int tile = *tileShared;
        if (tile >= ntiles) break;
        int node = tile * 64 + r;
        bool alive = node < n;
        float dd = 0.f;
        float s[8] = {0, 0, 0, 0, 0, 0, 0, 0};
        if (alive) {
            gather32(starts, es, (const uint4*)g, node, lane, s);
            dd = dis[node];
#pragma unroll
            for (int i = 0; i < 8; ++i) Xs[r][c0 + i] = dd * s[i];
        }
        __syncthreads();
        if (alive) {
            float am[8], al[8];
#pragma unroll
            for (int i = 0; i < 8; ++i) { am[i] = bm[i]; al[i] = bl[i]; }
#pragma unroll 4
            for (int k = 0; k < 32; ++k) {
                float xv = Xs[r][k];
#pragma unroll
                for (int i = 0; i < 8; ++i) {
                    am[i] += xv * Ws[k][c0 + i];
                    al[i] += xv * Ws[k][32 + c0 + i];
                }
            }
            float4* om = (float4*)out + (size_t)node * 8 + lane * 2;
            om[0] = make_float4(am[0], am[1], am[2], am[3]);
            om[1] = make_float4(am[4], am[5], am[6], am[7]);
            float4* ol = (float4*)(out + (size_t)n * 32) + (size_t)node * 8 + lane * 2;
            ol[0] = make_float4(al[0], al[1], al[2], al[3]);
            ol[1] = make_float4(al[4], al[5], al[6], al[7]);
        }
    }
}

// ---- cooperative 3-layer kernel --------------------------------------------
__global__ __launch_bounds__(256, 4)
void k_layers(const int* starts, const int* es, const float* dis,
              __half* gA, __half* gB,
              const float* W1, const float* b1,
              const float* W2, const float* b2,
              const float* Wmu, const float* Wlv,
              const float* bmu, const float* blv,
              float* out, int* tctr, int n, int ntiles) {
    __shared__ float Ws[32][66];
    __shared__ float Xs[64][33];
    __shared__ int   tileShared;
    cg::grid_group grid = cg::this_grid();
    // layer 1: gB = fp16(dis*relu(agg(gA)@W1+b1))
    hidden_phase(starts, es, dis, gA, W1, b1, gB, n, ntiles, tctr + 0, Ws, Xs, &tileShared);
    __threadfence();
    grid.sync();
    // layer 2: gA = fp16(dis*relu(agg(gB)@W2+b2))   (gA fully consumed above)
    hidden_phase(starts, es, dis, gB, W2, b2, gA, n, ntiles, tctr + 1, Ws, Xs, &tileShared);
    __threadfence();
    grid.sync();
    // mu/logvar from agg(gA)
    final_phase(starts, es, dis, gA, Wmu, Wlv, bmu, blv, out, n, ntiles, tctr + 2, Ws, Xs, &tileShared);
}

// ---- launch ----------------------------------------------------------------

extern "C" void kernel_launch(void* const* d_in, const int* in_sizes, int n_in,
                              void* d_out, int out_size, void* d_ws, size_t ws_size,
                              hipStream_t stream) {
    const float* x   = (const float*)d_in[0];
    const int*   ei  = (const int*)d_in[1];
    const float* W1  = (const float*)d_in[2];
    const float* b1  = (const float*)d_in[3];
    const float* W2  = (const float*)d_in[4];
    const float* b2  = (const float*)d_in[5];
    const float* Wmu = (const float*)d_in[6];
    const float* bmu = (const float*)d_in[7];
    const float* Wlv = (const float*)d_in[8];
    const float* blv = (const float*)d_in[9];
    float* out = (float*)d_out;

    int n = in_sizes[0] / 32;   // 100000
    int E = in_sizes[1] / 2;    // 1600000
    const int* src = ei;
    const int* dst = ei + E;
    int nbuck = (n + BK - 1) >> BK_BITS;   // 196 (<= 256)

    // workspace layout (all segments 16B-aligned)
    int*    bcur   = (int*)d_ws;                      // 256
    int*    tctr   = bcur + 256;                      // 3 tile counters (+pad)
    int     npad   = (n + 4) & ~3;
    int*    starts = bcur + 272;                      // n+1 (padded), 16B-aligned
    float*  dis    = (float*)(starts + npad);         // n
    int*    es     = (int*)(dis + n);                 // E
    __half* gA     = (__half*)(es + E);               // n*32 fp16
    __half* gB     = gA + (size_t)n * 32;             // n*32 fp16
    int*    ebuf   = (int*)(gB + (size_t)n * 32);     // 256*CAP ints (16.8 MB)

    int nblk   = (E + CHUNK - 1) / CHUNK;
    int ntiles = (n + 63) / 64;            // 1563

    // ---- edge preprocessing ----
    hipMemsetAsync(bcur, 0, 272 * sizeof(int), stream);
    k_bucket<<<nblk, 256, 0, stream>>>(src, dst, bcur, ebuf, E);
    k_finalize<<<nbuck, BK, 0, stream>>>(bcur, starts, dis, ebuf, es, x, gA, n, E);

    // ---- all three layers in one cooperative kernel ----
    static int coopBlocks = 0;
    if (coopBlocks == 0) {
        int mb = 0;
        if (hipOccupancyMaxActiveBlocksPerMultiprocessor(&mb, k_layers, 256, 0) != hipSuccess || mb < 1)
            mb = 4;                         // launch_bounds guarantees 4
        coopBlocks = mb * 256;              // 256 CUs on MI355X
    }
    int cgrid = coopBlocks < ntiles ? coopBlocks : ntiles;
    void* kargs[] = {(void*)&starts, (void*)&es, (void*)&dis, (void*)&gA, (void*)&gB,
                     (void*)&W1, (void*)&b1, (void*)&W2, (void*)&b2,
                     (void*)&Wmu, (void*)&Wlv, (void*)&bmu, (void*)&blv,
                     (void*)&out, (void*)&tctr, (void*)&n, (void*)&ntiles};
    hipLaunchCooperativeKernel(k_layers, dim3(cgrid), dim3(256), kargs, 0, stream);
}

// Round 3
// 281.756 us; speedup vs baseline: 1.8362x; 1.8362x over previous
//
#include <hip/hip_runtime.h>
#include <hip/hip_fp16.h>

// ---------------------------------------------------------------------------
// VGAE encoder, gather-form, fp16 gather table.
//   a[i] = dis_i*(g[i] + sum_{e:dst=i} g[src_e]),  g = fp16(dis (.) h)
// R12: agg+GEMM fused per 64-node block via LDS epilogue (294 -> 249 us).
// R13 FAILED: coop mega-kernel (grid.sync) = 517 us. Counters: VALUBusy 4%,
//   Occupancy 48% -> gather is latency/TLP-bound; coop's 4 blocks/CU halved
//   TLP and the atomic tile dispenser serialized tiles. LESSON: never trade
//   occupancy for dispatch-count on a latency-bound kernel.
// R14: split kernels restored + DEGREE-SORTED node permutation. k_finalize
//   counting-sorts each 512-node bucket by degree (cv already in register);
//   fused kernels walk nodes in perm order so each wave's 16 nodes have
//   ~equal degree -> uniform gather trip counts, no idle lanes. Per-node
//   edge order unchanged -> bit-identical output.
//   NT loads ONLY on read-once streams (src/dst). NT stores banned (R10).
// ---------------------------------------------------------------------------

#define BK_BITS 9
#define BK      (1 << BK_BITS)     // 512 dst nodes per bucket
#define BMASK   (BK - 1)
#define EPT     16
#define CHUNK   (256 * EPT)        // 4096 edges per block
#define CAP     16384              // bucket capacity (mean 8192, max ~8.6k)

typedef int   vint4   __attribute__((ext_vector_type(4)));
typedef uint  vuint4  __attribute__((ext_vector_type(4)));
typedef float vfloat4 __attribute__((ext_vector_type(4)));

#define NTL(p) __builtin_nontemporal_load(p)

// ---- pass A: scatter edges into capacity-padded dst-buckets ----------------
__global__ void k_bucket(const int* __restrict__ src, const int* __restrict__ dst,
                         int* __restrict__ bcur, int* __restrict__ ebuf, int E) {
    __shared__ int lcnt[256];
    __shared__ int lbase[256];
    int t = threadIdx.x;
    lcnt[t] = 0;
    __syncthreads();
    int e0 = blockIdx.x * CHUNK;
    int pk[EPT];
#pragma unroll
    for (int i = 0; i < EPT; ++i) {
        int e = e0 + i * 256 + t;
        pk[i] = -1;
        if (e < E) {
            int d = NTL(dst + e);
            int b = d >> BK_BITS;
            int off = atomicAdd(&lcnt[b], 1);          // off < CHUNK = 4096
            pk[i] = (b << 21) | (off << BK_BITS) | (d & BMASK);
        }
    }
    __syncthreads();
    lbase[t] = t * CAP + atomicAdd(&bcur[t], lcnt[t]);
    __syncthreads();
#pragma unroll
    for (int i = 0; i < EPT; ++i) {
        int e = e0 + i * 256 + t;
        if (e < E) {
            int b   = pk[i] >> 21;
            int off = (pk[i] >> BK_BITS) & 4095;
            int dl  = pk[i] & BMASK;
            int pos = lbase[b] + off;
            if (pos < (b + 1) * CAP)                  // overflow guard (never hit)
                ebuf[pos] = (NTL(src + e) << BK_BITS) | dl;
        }
    }
}

// ---- pass B: per-bucket finalize: starts, dis, sorted src, perm, g0 --------
__global__ void k_finalize(const int* __restrict__ bcur, int* __restrict__ starts,
                           float* __restrict__ dis, const int* __restrict__ ebuf,
                           int* __restrict__ es, const float* __restrict__ x,
                           __half* __restrict__ g0, int* __restrict__ perm,
                           int n, int E) {
    __shared__ int   hist[BK];
    __shared__ int   sc[BK];
    __shared__ int   sb[256];
    __shared__ float disL[BK];
    __shared__ int   dh[64];    // clipped-degree histogram
    __shared__ int   db[64];    // descending-degree base offsets
    __shared__ int   dc[64];    // rank cursors
    int b = blockIdx.x, t = threadIdx.x;
    if (t < 256) sb[t] = min(bcur[t], CAP);
    hist[t] = 0;
    if (t < 64) { dh[t] = 0; dc[t] = 0; }
    __syncthreads();
    for (int o = 1; o < 256; o <<= 1) {
        int xv = 0;
        if (t < 256 && t >= o) xv = sb[t - o];
        __syncthreads();
        if (t < 256) sb[t] += xv;
        __syncthreads();
    }
    int cnt = min(bcur[b], CAP);
    int beg = sb[b] - cnt;                  // exclusive scan at b
    const int* eb = ebuf + (size_t)b * CAP;
    for (int j = t; j < cnt; j += BK)
        atomicAdd(&hist[eb[j] & BMASK], 1);
    __syncthreads();
    int cv = hist[t];
    sc[t] = cv;
    __syncthreads();
    for (int o = 1; o < BK; o <<= 1) {
        int xv = (t >= o) ? sc[t - o] : 0;
        __syncthreads();
        sc[t] += xv;
        __syncthreads();
    }
    int excl = sc[t] - cv;
    int gnode = (b << BK_BITS) + t;
    float dv = rsqrtf((float)cv + 1.0f);    // +1 = self loop
    disL[t] = dv;
    if (gnode < n) {
        starts[gnode] = beg + excl;
        dis[gnode] = dv;
    }
    if (b == 0 && t == 0) starts[n] = E;
    // ---- degree-sort this bucket's 512 nodes into perm (descending) ----
    int dcl = min(cv, 63);
    atomicAdd(&dh[dcl], 1);
    __syncthreads();
    if (t < 64) {                           // base = count of strictly-higher bins
        int v = 0;
        for (int d = t + 1; d < 64; ++d) v += dh[d];
        db[t] = v;
    }
    __syncthreads();
    int rank = db[dcl] + atomicAdd(&dc[dcl], 1);
    perm[(b << BK_BITS) + rank] = gnode;    // invalid gnodes (deg 0) sort last
    // ---- scatter edges into dst-sorted es ----
    hist[t] = excl;                         // reuse as cursor
    __syncthreads();
    for (int j = t; j < cnt; j += BK) {
        int v = eb[j];
        int off = atomicAdd(&hist[v & BMASK], 1);
        es[beg + off] = v >> BK_BITS;       // normal store: L2 combines
    }
    // g0 = fp16(dis (.) x) for this bucket's nodes (coalesced 8 B stores)
    int node0 = b << BK_BITS;
    const float4* x4 = (const float4*)x;
    uint2* g2 = (uint2*)g0;
    for (int idx = t; idx < BK * 8; idx += BK) {
        int r = idx >> 3, lane = idx & 7;
        int nd = node0 + r;
        if (nd < n) {
            float d = disL[r];
            float4 v = x4[(size_t)nd * 8 + lane];
            __half2 lo = __floats2half2_rn(d * v.x, d * v.y);
            __half2 hi = __floats2half2_rn(d * v.z, d * v.w);
            uint2 u;
            u.x = *(unsigned int*)&lo;
            u.y = *(unsigned int*)&hi;
            g2[(size_t)nd * 8 + lane] = u;
        }
    }
}

// ---- gather helper: accumulate 8 halves into fp32 --------------------------
__device__ inline void acc8(uint4 u, float* s) {
    __half2 h0 = *(__half2*)&u.x, h1 = *(__half2*)&u.y;
    __half2 h2 = *(__half2*)&u.z, h3 = *(__half2*)&u.w;
    float2 f0 = __half22float2(h0), f1 = __half22float2(h1);
    float2 f2 = __half22float2(h2), f3 = __half22float2(h3);
    s[0] += f0.x; s[1] += f0.y; s[2] += f1.x; s[3] += f1.y;
    s[4] += f2.x; s[5] += f2.y; s[6] += f3.x; s[7] += f3.y;
}

// ---- gather core: s[8] = self + sum over edge list (fp32 accum) ------------
__device__ inline void gather32(const int* __restrict__ starts,
                                const int* __restrict__ es,
                                const uint4* __restrict__ g4,
                                int node, int lane, float* s) {
    acc8(g4[(size_t)node * 4 + lane], s);  // self term
    int j = starts[node], end = starts[node + 1];
    while (j < end && (j & 3)) {           // align to int4 boundary
        acc8(g4[(size_t)es[j] * 4 + lane], s);
        ++j;
    }
    for (; j + 8 <= end; j += 8) {         // 8 gathers in flight
        int4 e0 = *(const int4*)(es + j);
        int4 e1 = *(const int4*)(es + j + 4);
        uint4 u0 = g4[(size_t)e0.x * 4 + lane];
        uint4 u1 = g4[(size_t)e0.y * 4 + lane];
        uint4 u2 = g4[(size_t)e0.z * 4 + lane];
        uint4 u3 = g4[(size_t)e0.w * 4 + lane];
        uint4 u4 = g4[(size_t)e1.x * 4 + lane];
        uint4 u5 = g4[(size_t)e1.y * 4 + lane];
        uint4 u6 = g4[(size_t)e1.z * 4 + lane];
        uint4 u7 = g4[(size_t)e1.w * 4 + lane];
        acc8(u0, s); acc8(u1, s); acc8(u2, s); acc8(u3, s);
        acc8(u4, s); acc8(u5, s); acc8(u6, s); acc8(u7, s);
    }
    if (j + 4 <= end) {
        int4 e0 = *(const int4*)(es + j);
        uint4 u0 = g4[(size_t)e0.x * 4 + lane];
        uint4 u1 = g4[(size_t)e0.y * 4 + lane];
        uint4 u2 = g4[(size_t)e0.z * 4 + lane];
        uint4 u3 = g4[(size_t)e0.w * 4 + lane];
        acc8(u0, s); acc8(u1, s); acc8(u2, s); acc8(u3, s);
        j += 4;
    }
    for (; j < end; ++j) acc8(g4[(size_t)es[j] * 4 + lane], s);
}

// ---- fused hidden layer: gout = fp16(dis (.) relu(agg(g) @ W + b)) ---------
// 64 nodes/block via perm (degree-uniform waves), 4 lanes/node.
__global__ __launch_bounds__(256)
void k_fused16(const int* __restrict__ starts, const int* __restrict__ es,
               const float* __restrict__ dis, const __half* __restrict__ g,
               const float* __restrict__ W, const float* __restrict__ bias,
               __half* __restrict__ gout, const int* __restrict__ perm, int n) {
    __shared__ float Ws[32][33];
    __shared__ float Xs[64][33];
    int t = threadIdx.x;
    for (int i = t; i < 1024; i += 256) Ws[i >> 5][i & 31] = W[i];
    int r = t >> 2, lane = t & 3;
    int node = perm[blockIdx.x * 64 + r];
    bool alive = node < n;
    float dd = 0.f;
    if (alive) {
        float s[8] = {0, 0, 0, 0, 0, 0, 0, 0};
        gather32(starts, es, (const uint4*)g, node, lane, s);
        dd = dis[node];
#pragma unroll
        for (int i = 0; i < 8; ++i) Xs[r][lane * 8 + i] = dd * s[i];
    }
    __syncthreads();                       // covers Ws and Xs
    if (alive) {
        int c0 = lane * 8;
        float acc[8];
#pragma unroll
        for (int i = 0; i < 8; ++i) acc[i] = bias[c0 + i];
#pragma unroll 8
        for (int k = 0; k < 32; ++k) {
            float xv = Xs[r][k];
#pragma unroll
            for (int i = 0; i < 8; ++i) acc[i] += xv * Ws[k][c0 + i];
        }
        __half2 h0 = __floats2half2_rn(dd * fmaxf(acc[0], 0.f), dd * fmaxf(acc[1], 0.f));
        __half2 h1 = __floats2half2_rn(dd * fmaxf(acc[2], 0.f), dd * fmaxf(acc[3], 0.f));
        __half2 h2 = __floats2half2_rn(dd * fmaxf(acc[4], 0.f), dd * fmaxf(acc[5], 0.f));
        __half2 h3 = __floats2half2_rn(dd * fmaxf(acc[6], 0.f), dd * fmaxf(acc[7], 0.f));
        uint4 u;
        u.x = *(unsigned int*)&h0; u.y = *(unsigned int*)&h1;
        u.z = *(unsigned int*)&h2; u.w = *(unsigned int*)&h3;
        ((uint4*)gout)[(size_t)node * 4 + lane] = u;
    }
}

// ---- fused output layer: out = [agg(g) @ Wmu + bmu | agg(g) @ Wlv + blv] ---
__global__ __launch_bounds__(256)
void k_fused_final(const int* __restrict__ starts, const int* __restrict__ es,
                   const float* __restrict__ dis, const __half* __restrict__ g,
                   const float* __restrict__ Wmu, const float* __restrict__ Wlv,
                   const float* __restrict__ bmu, const float* __restrict__ blv,
                   float* __restrict__ out, const int* __restrict__ perm, int n) {
    __shared__ float Ws[32][66];           // [k][c], mu cols 0-31, lv cols 32-63
    __shared__ float Xs[64][33];
    int t = threadIdx.x;
    for (int i = t; i < 1024; i += 256) {
        Ws[i >> 5][i & 31]        = Wmu[i];
        Ws[i >> 5][32 + (i & 31)] = Wlv[i];
    }
    int r = t >> 2, lane = t & 3;
    int node = perm[blockIdx.x * 64 + r];
    bool alive = node < n;
    if (alive) {
        float s[8] = {0, 0, 0, 0, 0, 0, 0, 0};
        gather32(starts, es, (const uint4*)g, node, lane, s);
        float dd = dis[node];
#pragma unroll
        for (int i = 0; i < 8; ++i) Xs[r][lane * 8 + i] = dd * s[i];
    }
    __syncthreads();
    if (alive) {
        int c0 = lane * 8;
        float am[8], al[8];
#pragma unroll
        for (int i = 0; i < 8; ++i) { am[i] = bmu[c0 + i]; al[i] = blv[c0 + i]; }
#pragma unroll 4
        for (int k = 0; k < 32; ++k) {
            float xv = Xs[r][k];
#pragma unroll
            for (int i = 0; i < 8; ++i) {
                am[i] += xv * Ws[k][c0 + i];
                al[i] += xv * Ws[k][32 + c0 + i];
            }
        }
        float4* om = (float4*)out + (size_t)node * 8 + lane * 2;
        om[0] = make_float4(am[0], am[1], am[2], am[3]);
        om[1] = make_float4(am[4], am[5], am[6], am[7]);
        float4* ol = (float4*)(out + (size_t)n * 32) + (size_t)node * 8 + lane * 2;
        ol[0] = make_float4(al[0], al[1], al[2], al[3]);
        ol[1] = make_float4(al[4], al[5], al[6], al[7]);
    }
}

// ---- launch ----------------------------------------------------------------

extern "C" void kernel_launch(void* const* d_in, const int* in_sizes, int n_in,
                              void* d_out, int out_size, void* d_ws, size_t ws_size,
                              hipStream_t stream) {
    const float* x   = (const float*)d_in[0];
    const int*   ei  = (const int*)d_in[1];
    const float* W1  = (const float*)d_in[2];
    const float* b1  = (const float*)d_in[3];
    const float* W2  = (const float*)d_in[4];
    const float* b2  = (const float*)d_in[5];
    const float* Wmu = (const float*)d_in[6];
    const float* bmu = (const float*)d_in[7];
    const float* Wlv = (const float*)d_in[8];
    const float* blv = (const float*)d_in[9];
    float* out = (float*)d_out;

    int n = in_sizes[0] / 32;   // 100000
    int E = in_sizes[1] / 2;    // 1600000
    const int* src = ei;
    const int* dst = ei + E;
    int nbuck = (n + BK - 1) >> BK_BITS;   // 196 (<= 256)

    // workspace layout (all segments 16B-aligned)
    int*    bcur   = (int*)d_ws;                      // 256
    int     npad   = (n + 4) & ~3;
    int*    starts = bcur + 256;                      // n+1 (padded)
    float*  dis    = (float*)(starts + npad);         // n
    int*    es     = (int*)(dis + n);                 // E
    __half* gA     = (__half*)(es + E);               // n*32 fp16
    __half* gB     = gA + (size_t)n * 32;             // n*32 fp16
    int*    perm   = (int*)(gB + (size_t)n * 32);     // nbuck*512
    int*    ebuf   = perm + (size_t)nbuck * BK;       // 256*CAP ints (16.8 MB)

    int nblk  = (E + CHUNK - 1) / CHUNK;
    int agrid = nbuck * (BK / 64);         // 64 perm entries per block

    // ---- edge preprocessing ----
    hipMemsetAsync(bcur, 0, 256 * sizeof(int), stream);
    k_bucket<<<nblk, 256, 0, stream>>>(src, dst, bcur, ebuf, E);
    k_finalize<<<nbuck, BK, 0, stream>>>(bcur, starts, dis, ebuf, es, x, gA, perm, n, E);

    // ---- layer 1 (agg + gemm fused) ----
    k_fused16<<<agrid, 256, 0, stream>>>(starts, es, dis, gA, W1, b1, gB, perm, n);
    // ---- layer 2 ----
    k_fused16<<<agrid, 256, 0, stream>>>(starts, es, dis, gB, W2, b2, gA, perm, n);
    // ---- mu/logvar ----
    k_fused_final<<<agrid, 256, 0, stream>>>(starts, es, dis, gA, Wmu, Wlv, bmu, blv, out, perm, n);
}

// Round 5
// 255.864 us; speedup vs baseline: 2.0220x; 1.1012x over previous
//
#include <hip/hip_runtime.h>
#include <hip/hip_fp16.h>

// ---------------------------------------------------------------------------
// VGAE encoder, gather-form, fp16 gather table.
//   a[i] = dis_i*(g[i] + sum_{e:dst=i} g[src_e]),  g = fp16(dis (.) h)
// R12: agg+GEMM fused per 64-node block via LDS epilogue (294 -> 249 us).
// R13 FAILED: coop mega-kernel = 517 us (occupancy halved; latency-bound).
// R14 FAILED: global degree-sort perm = 282 us (+33): scattered self/out/es
//   locality; gather is request-throughput-bound, uniform waves don't help.
// R15: perm reverted (layer kernels = R12 exact). PREPROCESSING parallelized:
//   counters showed ~95-100 us hidden in k_bucket (6 waves/CU) + k_finalize
//   (196 blocks = 0.77/CU, GPU 3/4 idle). k_bucket -> 512 thr/block (2x
//   waves). k_finalize -> k_finalize2: nbuck*8 blocks, each 64-node window;
//   full-bucket hist recomputed per block (redundant ebuf streams are
//   L2-shared), scatter + starts/dis/g0 only for own window.
// R16: R15 resubmitted verbatim — R15 bench was an infra failure (container
//   acquire failed twice, no kernel stage ran); audit found no fault/hang
//   hazard in the kernel itself.
//   NT loads ONLY on read-once streams (src/dst). NT stores banned (R10).
// ---------------------------------------------------------------------------

#define BK_BITS 9
#define BK      (1 << BK_BITS)     // 512 dst nodes per bucket
#define BMASK   (BK - 1)
#define BTHR    512                // k_bucket threads
#define EPT     8
#define CHUNK   (BTHR * EPT)       // 4096 edges per block
#define CAP     16384              // bucket capacity (mean 8192, max ~8.6k)

typedef int   vint4   __attribute__((ext_vector_type(4)));
typedef uint  vuint4  __attribute__((ext_vector_type(4)));
typedef float vfloat4 __attribute__((ext_vector_type(4)));

#define NTL(p) __builtin_nontemporal_load(p)

// ---- pass A: scatter edges into capacity-padded dst-buckets ----------------
__global__ __launch_bounds__(BTHR)
void k_bucket(const int* __restrict__ src, const int* __restrict__ dst,
              int* __restrict__ bcur, int* __restrict__ ebuf, int E) {
    __shared__ int lcnt[256];
    __shared__ int lbase[256];
    int t = threadIdx.x;
    if (t < 256) lcnt[t] = 0;
    __syncthreads();
    int e0 = blockIdx.x * CHUNK;
    int pk[EPT];
#pragma unroll
    for (int i = 0; i < EPT; ++i) {
        int e = e0 + i * BTHR + t;
        pk[i] = -1;
        if (e < E) {
            int d = NTL(dst + e);
            int b = d >> BK_BITS;
            int off = atomicAdd(&lcnt[b], 1);          // off < CHUNK = 4096
            pk[i] = (b << 21) | (off << BK_BITS) | (d & BMASK);
        }
    }
    __syncthreads();
    if (t < 256) lbase[t] = t * CAP + atomicAdd(&bcur[t], lcnt[t]);
    __syncthreads();
#pragma unroll
    for (int i = 0; i < EPT; ++i) {
        int e = e0 + i * BTHR + t;
        if (e < E) {
            int b   = pk[i] >> 21;
            int off = (pk[i] >> BK_BITS) & 4095;
            int dl  = pk[i] & BMASK;
            int pos = lbase[b] + off;
            if (pos < (b + 1) * CAP)                  // overflow guard (never hit)
                ebuf[pos] = (NTL(src + e) << BK_BITS) | dl;
        }
    }
}

// ---- pass B: per-WINDOW finalize (8 blocks per bucket, 64 nodes each) ------
// Each block: scan bcur -> bucket base; full-bucket 512-bin histogram + scan
// (cheap, redundant across the 8 siblings -> L2-shared streams); then
// starts/dis/g0 + edge scatter for its own 64-node window only.
__global__ __launch_bounds__(256)
void k_finalize2(const int* __restrict__ bcur, int* __restrict__ starts,
                 float* __restrict__ dis, const int* __restrict__ ebuf,
                 int* __restrict__ es, const float* __restrict__ x,
                 __half* __restrict__ g0, int n, int E) {
    __shared__ int   sb[256];      // bucket-total scan, then pair-sum scan
    __shared__ int   hist[BK];     // per-node counts (bucket-wide)
    __shared__ int   hsc[BK];      // exclusive offsets (bucket-wide)
    __shared__ int   curs[64];     // window scatter cursors
    __shared__ float disw[64];     // window dis values
    int b = blockIdx.x >> 3;       // bucket
    int w = blockIdx.x & 7;        // 64-node window within bucket
    int t = threadIdx.x;
    // bucket base via scan of bcur
    sb[t] = min(bcur[t], CAP);
    __syncthreads();
    for (int o = 1; o < 256; o <<= 1) {
        int v = (t >= o) ? sb[t - o] : 0;
        __syncthreads();
        sb[t] += v;
        __syncthreads();
    }
    int cnt = min(bcur[b], CAP);
    int beg = sb[b] - cnt;         // exclusive scan at b
    // full-bucket histogram
    hist[t] = 0; hist[t + 256] = 0;
    __syncthreads();
    const int* eb = ebuf + (size_t)b * CAP;
    for (int j = t; j < cnt; j += 256)
        atomicAdd(&hist[eb[j] & BMASK], 1);
    __syncthreads();
    // scan 512 bins with 256 threads (pairwise)
    int a0 = hist[2 * t], a1 = hist[2 * t + 1];
    int ps = a0 + a1;
    sb[t] = ps;
    __syncthreads();
    for (int o = 1; o < 256; o <<= 1) {
        int v = (t >= o) ? sb[t - o] : 0;
        __syncthreads();
        sb[t] += v;
        __syncthreads();
    }
    int ebase = sb[t] - ps;        // exclusive over pairs
    hsc[2 * t]     = ebase;
    hsc[2 * t + 1] = ebase + a0;
    __syncthreads();
    // window outputs: starts, dis
    if (t < 64) {
        int r = w * 64 + t;        // bucket-relative node
        int gnode = (b << BK_BITS) + r;
        int cv = hist[r];
        float dv = rsqrtf((float)cv + 1.0f);   // +1 = self loop
        disw[t] = dv;
        if (gnode < n) {
            starts[gnode] = beg + hsc[r];
            dis[gnode] = dv;
        }
        curs[t] = hsc[r];          // scatter cursor (bucket-relative)
    }
    if (blockIdx.x == 0 && t == 0) starts[n] = E;
    __syncthreads();
    // scatter this window's edges into dst-sorted es
    for (int j = t; j < cnt; j += 256) {
        int v = eb[j];
        int dl = v & BMASK;
        if ((dl >> 6) == w) {
            int off = atomicAdd(&curs[dl & 63], 1);
            es[beg + off] = v >> BK_BITS;     // normal store: L2 combines
        }
    }
    // g0 = fp16(dis (.) x) for window nodes (coalesced 8 B stores)
    int node0 = (b << BK_BITS) + w * 64;
    const float4* x4 = (const float4*)x;
    uint2* g2 = (uint2*)g0;
    for (int idx = t; idx < 64 * 8; idx += 256) {
        int r = idx >> 3, ln = idx & 7;
        int nd = node0 + r;
        if (nd < n) {
            float d = disw[r];
            float4 v = x4[(size_t)nd * 8 + ln];
            __half2 lo = __floats2half2_rn(d * v.x, d * v.y);
            __half2 hi = __floats2half2_rn(d * v.z, d * v.w);
            uint2 u;
            u.x = *(unsigned int*)&lo;
            u.y = *(unsigned int*)&hi;
            g2[(size_t)nd * 8 + ln] = u;
        }
    }
}

// ---- gather helper: accumulate 8 halves into fp32 --------------------------
__device__ inline void acc8(uint4 u, float* s) {
    __half2 h0 = *(__half2*)&u.x, h1 = *(__half2*)&u.y;
    __half2 h2 = *(__half2*)&u.z, h3 = *(__half2*)&u.w;
    float2 f0 = __half22float2(h0), f1 = __half22float2(h1);
    float2 f2 = __half22float2(h2), f3 = __half22float2(h3);
    s[0] += f0.x; s[1] += f0.y; s[2] += f1.x; s[3] += f1.y;
    s[4] += f2.x; s[5] += f2.y; s[6] += f3.x; s[7] += f3.y;
}

// ---- gather core: s[8] = self + sum over edge list (fp32 accum) ------------
__device__ inline void gather32(const int* __restrict__ starts,
                                const int* __restrict__ es,
                                const uint4* __restrict__ g4,
                                int node, int lane, float* s) {
    acc8(g4[(size_t)node * 4 + lane], s);  // self term
    int j = starts[node], end = starts[node + 1];
    while (j < end && (j & 3)) {           // align to int4 boundary
        acc8(g4[(size_t)es[j] * 4 + lane], s);
        ++j;
    }
    for (; j + 8 <= end; j += 8) {         // 8 gathers in flight
        int4 e0 = *(const int4*)(es + j);
        int4 e1 = *(const int4*)(es + j + 4);
        uint4 u0 = g4[(size_t)e0.x * 4 + lane];
        uint4 u1 = g4[(size_t)e0.y * 4 + lane];
        uint4 u2 = g4[(size_t)e0.z * 4 + lane];
        uint4 u3 = g4[(size_t)e0.w * 4 + lane];
        uint4 u4 = g4[(size_t)e1.x * 4 + lane];
        uint4 u5 = g4[(size_t)e1.y * 4 + lane];
        uint4 u6 = g4[(size_t)e1.z * 4 + lane];
        uint4 u7 = g4[(size_t)e1.w * 4 + lane];
        acc8(u0, s); acc8(u1, s); acc8(u2, s); acc8(u3, s);
        acc8(u4, s); acc8(u5, s); acc8(u6, s); acc8(u7, s);
    }
    if (j + 4 <= end) {
        int4 e0 = *(const int4*)(es + j);
        uint4 u0 = g4[(size_t)e0.x * 4 + lane];
        uint4 u1 = g4[(size_t)e0.y * 4 + lane];
        uint4 u2 = g4[(size_t)e0.z * 4 + lane];
        uint4 u3 = g4[(size_t)e0.w * 4 + lane];
        acc8(u0, s); acc8(u1, s); acc8(u2, s); acc8(u3, s);
        j += 4;
    }
    for (; j < end; ++j) acc8(g4[(size_t)es[j] * 4 + lane], s);
}

// ---- fused hidden layer: gout = fp16(dis (.) relu(agg(g) @ W + b)) ---------
// 64 nodes/block, 4 lanes/node. Agg result (fp32, pre-fp16-quant!) goes to
// LDS; 32x32 GEMM epilogue reads Xs/Ws broadcast, ONE barrier total.
__global__ __launch_bounds__(256)
void k_fused16(const int* __restrict__ starts, const int* __restrict__ es,
               const float* __restrict__ dis, const __half* __restrict__ g,
               const float* __restrict__ W, const float* __restrict__ bias,
               __half* __restrict__ gout, int n) {
    __shared__ float Ws[32][33];
    __shared__ float Xs[64][33];
    int t = threadIdx.x;
    for (int i = t; i < 1024; i += 256) Ws[i >> 5][i & 31] = W[i];
    int r = t >> 2, lane = t & 3;
    int node = blockIdx.x * 64 + r;
    bool alive = node < n;
    float dd = 0.f;
    if (alive) {
        float s[8] = {0, 0, 0, 0, 0, 0, 0, 0};
        gather32(starts, es, (const uint4*)g, node, lane, s);
        dd = dis[node];
#pragma unroll
        for (int i = 0; i < 8; ++i) Xs[r][lane * 8 + i] = dd * s[i];
    }
    __syncthreads();                       // covers Ws and Xs
    if (alive) {
        int c0 = lane * 8;
        float acc[8];
#pragma unroll
        for (int i = 0; i < 8; ++i) acc[i] = bias[c0 + i];
#pragma unroll 8
        for (int k = 0; k < 32; ++k) {
            float xv = Xs[r][k];
#pragma unroll
            for (int i = 0; i < 8; ++i) acc[i] += xv * Ws[k][c0 + i];
        }
        __half2 h0 = __floats2half2_rn(dd * fmaxf(acc[0], 0.f), dd * fmaxf(acc[1], 0.f));
        __half2 h1 = __floats2half2_rn(dd * fmaxf(acc[2], 0.f), dd * fmaxf(acc[3], 0.f));
        __half2 h2 = __floats2half2_rn(dd * fmaxf(acc[4], 0.f), dd * fmaxf(acc[5], 0.f));
        __half2 h3 = __floats2half2_rn(dd * fmaxf(acc[6], 0.f), dd * fmaxf(acc[7], 0.f));
        uint4 u;
        u.x = *(unsigned int*)&h0; u.y = *(unsigned int*)&h1;
        u.z = *(unsigned int*)&h2; u.w = *(unsigned int*)&h3;
        ((uint4*)gout)[(size_t)node * 4 + lane] = u;
    }
}

// ---- fused output layer: out = [agg(g) @ Wmu + bmu | agg(g) @ Wlv + blv] ---
__global__ __launch_bounds__(256)
void k_fused_final(const int* __restrict__ starts, const int* __restrict__ es,
                   const float* __restrict__ dis, const __half* __restrict__ g,
                   const float* __restrict__ Wmu, const float* __restrict__ Wlv,
                   const float* __restrict__ bmu, const float* __restrict__ blv,
                   float* __restrict__ out, int n) {
    __shared__ float Ws[32][66];           // [k][c], mu cols 0-31, lv cols 32-63
    __shared__ float Xs[64][33];
    int t = threadIdx.x;
    for (int i = t; i < 1024; i += 256) {
        Ws[i >> 5][i & 31]        = Wmu[i];
        Ws[i >> 5][32 + (i & 31)] = Wlv[i];
    }
    int r = t >> 2, lane = t & 3;
    int node = blockIdx.x * 64 + r;
    bool alive = node < n;
    if (alive) {
        float s[8] = {0, 0, 0, 0, 0, 0, 0, 0};
        gather32(starts, es, (const uint4*)g, node, lane, s);
        float dd = dis[node];
#pragma unroll
        for (int i = 0; i < 8; ++i) Xs[r][lane * 8 + i] = dd * s[i];
    }
    __syncthreads();
    if (alive) {
        int c0 = lane * 8;
        float am[8], al[8];
#pragma unroll
        for (int i = 0; i < 8; ++i) { am[i] = bmu[c0 + i]; al[i] = blv[c0 + i]; }
#pragma unroll 4
        for (int k = 0; k < 32; ++k) {
            float xv = Xs[r][k];
#pragma unroll
            for (int i = 0; i < 8; ++i) {
                am[i] += xv * Ws[k][c0 + i];
                al[i] += xv * Ws[k][32 + c0 + i];
            }
        }
        float4* om = (float4*)out + (size_t)node * 8 + lane * 2;
        om[0] = make_float4(am[0], am[1], am[2], am[3]);
        om[1] = make_float4(am[4], am[5], am[6], am[7]);
        float4* ol = (float4*)(out + (size_t)n * 32) + (size_t)node * 8 + lane * 2;
        ol[0] = make_float4(al[0], al[1], al[2], al[3]);
        ol[1] = make_float4(al[4], al[5], al[6], al[7]);
    }
}

// ---- launch ----------------------------------------------------------------

extern "C" void kernel_launch(void* const* d_in, const int* in_sizes, int n_in,
                              void* d_out, int out_size, void* d_ws, size_t ws_size,
                              hipStream_t stream) {
    const float* x   = (const float*)d_in[0];
    const int*   ei  = (const int*)d_in[1];
    const float* W1  = (const float*)d_in[2];
    const float* b1  = (const float*)d_in[3];
    const float* W2  = (const float*)d_in[4];
    const float* b2  = (const float*)d_in[5];
    const float* Wmu = (const float*)d_in[6];
    const float* bmu = (const float*)d_in[7];
    const float* Wlv = (const float*)d_in[8];
    const float* blv = (const float*)d_in[9];
    float* out = (float*)d_out;

    int n = in_sizes[0] / 32;   // 100000
    int E = in_sizes[1] / 2;    // 1600000
    const int* src = ei;
    const int* dst = ei + E;
    int nbuck = (n + BK - 1) >> BK_BITS;   // 196 (<= 256)

    // workspace layout (all segments 16B-aligned)
    int*    bcur   = (int*)d_ws;                      // 256
    int     npad   = (n + 4) & ~3;
    int*    starts = bcur + 256;                      // n+1 (padded)
    float*  dis    = (float*)(starts + npad);         // n
    int*    es     = (int*)(dis + n);                 // E
    __half* gA     = (__half*)(es + E);               // n*32 fp16
    __half* gB     = gA + (size_t)n * 32;             // n*32 fp16
    int*    ebuf   = (int*)(gB + (size_t)n * 32);     // 256*CAP ints (16.8 MB)

    int nblk  = (E + CHUNK - 1) / CHUNK;   // 391
    int agrid = (n + 63) / 64;             // 1563

    // ---- edge preprocessing ----
    hipMemsetAsync(bcur, 0, 256 * sizeof(int), stream);
    k_bucket<<<nblk, BTHR, 0, stream>>>(src, dst, bcur, ebuf, E);
    k_finalize2<<<nbuck * 8, 256, 0, stream>>>(bcur, starts, dis, ebuf, es, x, gA, n, E);

    // ---- layer 1 (agg + gemm fused) ----
    k_fused16<<<agrid, 256, 0, stream>>>(starts, es, dis, gA, W1, b1, gB, n);
    // ---- layer 2 ----
    k_fused16<<<agrid, 256, 0, stream>>>(starts, es, dis, gB, W2, b2, gA, n);
    // ---- mu/logvar ----
    k_fused_final<<<agrid, 256, 0, stream>>>(starts, es, dis, gA, Wmu, Wlv, bmu, blv, out, n);
}

// Round 6
// 244.805 us; speedup vs baseline: 2.1133x; 1.0452x over previous
//
#include <hip/hip_runtime.h>
#include <hip/hip_fp16.h>

// ---------------------------------------------------------------------------
// VGAE encoder, gather-form, fp16 gather table.
//   a[i] = dis_i*(g[i] + sum_{e:dst=i} g[src_e]),  g = fp16(dis (.) h)
// R12: agg+GEMM fused per 64-node block via LDS epilogue (294 -> 249 us).
// R13 FAILED: coop mega-kernel = 517 us (occupancy halved; latency-bound).
// R14 FAILED: global degree-sort perm = 282 us (+33): scattered locality.
// R15/R16 FAILED: preproc reorg (512-thr bucket + 8x-split finalize) = 255.9
//   (+6.7 vs R1): redundant per-window histograms ate the occupancy gain.
//   -> preproc REVERTED to R1-exact here.
// R17: gather MLP doubled: 16 outstanding uint4 gathers per wave (was 8).
//   R3 counters: k_fused_final 2.47 TB/s, VALU 14%, occ 33% -> request-
//   count-bound (Little's law: ~190 reqs in flight/CU at ~900cy latency).
//   All 16 loads issued before any accumulate; same accumulation order ->
//   bit-identical output.
//   NT loads ONLY on read-once streams (src/dst). NT stores banned (R10).
// ---------------------------------------------------------------------------

#define BK_BITS 9
#define BK      (1 << BK_BITS)     // 512 dst nodes per bucket
#define BMASK   (BK - 1)
#define EPT     16
#define CHUNK   (256 * EPT)        // 4096 edges per block
#define CAP     16384              // bucket capacity (mean 8192, max ~8.6k)

typedef int   vint4   __attribute__((ext_vector_type(4)));
typedef uint  vuint4  __attribute__((ext_vector_type(4)));
typedef float vfloat4 __attribute__((ext_vector_type(4)));

#define NTL(p) __builtin_nontemporal_load(p)

// ---- pass A: scatter edges into capacity-padded dst-buckets ----------------
__global__ void k_bucket(const int* __restrict__ src, const int* __restrict__ dst,
                         int* __restrict__ bcur, int* __restrict__ ebuf, int E) {
    __shared__ int lcnt[256];
    __shared__ int lbase[256];
    int t = threadIdx.x;
    lcnt[t] = 0;
    __syncthreads();
    int e0 = blockIdx.x * CHUNK;
    int pk[EPT];
#pragma unroll
    for (int i = 0; i < EPT; ++i) {
        int e = e0 + i * 256 + t;
        pk[i] = -1;
        if (e < E) {
            int d = NTL(dst + e);
            int b = d >> BK_BITS;
            int off = atomicAdd(&lcnt[b], 1);          // off < CHUNK = 4096
            pk[i] = (b << 21) | (off << BK_BITS) | (d & BMASK);
        }
    }
    __syncthreads();
    lbase[t] = t * CAP + atomicAdd(&bcur[t], lcnt[t]);
    __syncthreads();
#pragma unroll
    for (int i = 0; i < EPT; ++i) {
        int e = e0 + i * 256 + t;
        if (e < E) {
            int b   = pk[i] >> 21;
            int off = (pk[i] >> BK_BITS) & 4095;
            int dl  = pk[i] & BMASK;
            int pos = lbase[b] + off;
            if (pos < (b + 1) * CAP)                  // overflow guard (never hit)
                ebuf[pos] = (NTL(src + e) << BK_BITS) | dl;
        }
    }
}

// ---- pass B: per-bucket finalize: starts, dis, sorted src, g0 --------------
__global__ void k_finalize(const int* __restrict__ bcur, int* __restrict__ starts,
                           float* __restrict__ dis, const int* __restrict__ ebuf,
                           int* __restrict__ es, const float* __restrict__ x,
                           __half* __restrict__ g0, int n, int E) {
    __shared__ int   hist[BK];
    __shared__ int   sc[BK];
    __shared__ int   sb[256];
    __shared__ float disL[BK];
    int b = blockIdx.x, t = threadIdx.x;
    if (t < 256) sb[t] = min(bcur[t], CAP);
    hist[t] = 0;
    __syncthreads();
    for (int o = 1; o < 256; o <<= 1) {
        int xv = 0;
        if (t < 256 && t >= o) xv = sb[t - o];
        __syncthreads();
        if (t < 256) sb[t] += xv;
        __syncthreads();
    }
    int cnt = min(bcur[b], CAP);
    int beg = sb[b] - cnt;                  // exclusive scan at b
    const int* eb = ebuf + (size_t)b * CAP;
    for (int j = t; j < cnt; j += BK)
        atomicAdd(&hist[eb[j] & BMASK], 1);
    __syncthreads();
    int cv = hist[t];
    sc[t] = cv;
    __syncthreads();
    for (int o = 1; o < BK; o <<= 1) {
        int xv = (t >= o) ? sc[t - o] : 0;
        __syncthreads();
        sc[t] += xv;
        __syncthreads();
    }
    int excl = sc[t] - cv;
    int gnode = (b << BK_BITS) + t;
    float dv = rsqrtf((float)cv + 1.0f);    // +1 = self loop
    disL[t] = dv;
    if (gnode < n) {
        starts[gnode] = beg + excl;
        dis[gnode] = dv;
    }
    if (b == 0 && t == 0) starts[n] = E;
    hist[t] = excl;                         // reuse as cursor
    __syncthreads();
    for (int j = t; j < cnt; j += BK) {
        int v = eb[j];
        int off = atomicAdd(&hist[v & BMASK], 1);
        es[beg + off] = v >> BK_BITS;       // normal store: L2 combines
    }
    // g0 = fp16(dis (.) x) for this bucket's nodes (coalesced 8 B stores)
    int node0 = b << BK_BITS;
    const float4* x4 = (const float4*)x;
    uint2* g2 = (uint2*)g0;
    for (int idx = t; idx < BK * 8; idx += BK) {
        int r = idx >> 3, lane = idx & 7;
        int nd = node0 + r;
        if (nd < n) {
            float d = disL[r];
            float4 v = x4[(size_t)nd * 8 + lane];
            __half2 lo = __floats2half2_rn(d * v.x, d * v.y);
            __half2 hi = __floats2half2_rn(d * v.z, d * v.w);
            uint2 u;
            u.x = *(unsigned int*)&lo;
            u.y = *(unsigned int*)&hi;
            g2[(size_t)nd * 8 + lane] = u;
        }
    }
}

// ---- gather helper: accumulate 8 halves into fp32 --------------------------
__device__ inline void acc8(uint4 u, float* s) {
    __half2 h0 = *(__half2*)&u.x, h1 = *(__half2*)&u.y;
    __half2 h2 = *(__half2*)&u.z, h3 = *(__half2*)&u.w;
    float2 f0 = __half22float2(h0), f1 = __half22float2(h1);
    float2 f2 = __half22float2(h2), f3 = __half22float2(h3);
    s[0] += f0.x; s[1] += f0.y; s[2] += f1.x; s[3] += f1.y;
    s[4] += f2.x; s[5] += f2.y; s[6] += f3.x; s[7] += f3.y;
}

// ---- gather core: s[8] = self + sum over edge list (fp32 accum) ------------
// 16 gathers in flight (R17): all loads issued before any accumulate; the
// compiler's counted vmcnt lets acc8(u0) start as soon as load 0 retires.
// Accumulation order per node unchanged -> bit-identical.
__device__ inline void gather32(const int* __restrict__ starts,
                                const int* __restrict__ es,
                                const uint4* __restrict__ g4,
                                int node, int lane, float* s) {
    acc8(g4[(size_t)node * 4 + lane], s);  // self term
    int j = starts[node], end = starts[node + 1];
    while (j < end && (j & 3)) {           // align to int4 boundary
        acc8(g4[(size_t)es[j] * 4 + lane], s);
        ++j;
    }
    for (; j + 16 <= end; j += 16) {       // 16 gathers in flight
        int4 e0 = *(const int4*)(es + j);
        int4 e1 = *(const int4*)(es + j + 4);
        int4 e2 = *(const int4*)(es + j + 8);
        int4 e3 = *(const int4*)(es + j + 12);
        uint4 u0  = g4[(size_t)e0.x * 4 + lane];
        uint4 u1  = g4[(size_t)e0.y * 4 + lane];
        uint4 u2  = g4[(size_t)e0.z * 4 + lane];
        uint4 u3  = g4[(size_t)e0.w * 4 + lane];
        uint4 u4  = g4[(size_t)e1.x * 4 + lane];
        uint4 u5  = g4[(size_t)e1.y * 4 + lane];
        uint4 u6  = g4[(size_t)e1.z * 4 + lane];
        uint4 u7  = g4[(size_t)e1.w * 4 + lane];
        uint4 u8  = g4[(size_t)e2.x * 4 + lane];
        uint4 u9  = g4[(size_t)e2.y * 4 + lane];
        uint4 u10 = g4[(size_t)e2.z * 4 + lane];
        uint4 u11 = g4[(size_t)e2.w * 4 + lane];
        uint4 u12 = g4[(size_t)e3.x * 4 + lane];
        uint4 u13 = g4[(size_t)e3.y * 4 + lane];
        uint4 u14 = g4[(size_t)e3.z * 4 + lane];
        uint4 u15 = g4[(size_t)e3.w * 4 + lane];
        acc8(u0, s);  acc8(u1, s);  acc8(u2, s);  acc8(u3, s);
        acc8(u4, s);  acc8(u5, s);  acc8(u6, s);  acc8(u7, s);
        acc8(u8, s);  acc8(u9, s);  acc8(u10, s); acc8(u11, s);
        acc8(u12, s); acc8(u13, s); acc8(u14, s); acc8(u15, s);
    }
    if (j + 8 <= end) {
        int4 e0 = *(const int4*)(es + j);
        int4 e1 = *(const int4*)(es + j + 4);
        uint4 u0 = g4[(size_t)e0.x * 4 + lane];
        uint4 u1 = g4[(size_t)e0.y * 4 + lane];
        uint4 u2 = g4[(size_t)e0.z * 4 + lane];
        uint4 u3 = g4[(size_t)e0.w * 4 + lane];
        uint4 u4 = g4[(size_t)e1.x * 4 + lane];
        uint4 u5 = g4[(size_t)e1.y * 4 + lane];
        uint4 u6 = g4[(size_t)e1.z * 4 + lane];
        uint4 u7 = g4[(size_t)e1.w * 4 + lane];
        acc8(u0, s); acc8(u1, s); acc8(u2, s); acc8(u3, s);
        acc8(u4, s); acc8(u5, s); acc8(u6, s); acc8(u7, s);
        j += 8;
    }
    if (j + 4 <= end) {
        int4 e0 = *(const int4*)(es + j);
        uint4 u0 = g4[(size_t)e0.x * 4 + lane];
        uint4 u1 = g4[(size_t)e0.y * 4 + lane];
        uint4 u2 = g4[(size_t)e0.z * 4 + lane];
        uint4 u3 = g4[(size_t)e0.w * 4 + lane];
        acc8(u0, s); acc8(u1, s); acc8(u2, s); acc8(u3, s);
        j += 4;
    }
    for (; j < end; ++j) acc8(g4[(size_t)es[j] * 4 + lane], s);
}

// ---- fused hidden layer: gout = fp16(dis (.) relu(agg(g) @ W + b)) ---------
// 64 nodes/block, 4 lanes/node. Agg result (fp32, pre-fp16-quant!) goes to
// LDS; 32x32 GEMM epilogue reads Xs/Ws broadcast, ONE barrier total.
__global__ __launch_bounds__(256)
void k_fused16(const int* __restrict__ starts, const int* __restrict__ es,
               const float* __restrict__ dis, const __half* __restrict__ g,
               const float* __restrict__ W, const float* __restrict__ bias,
               __half* __restrict__ gout, int n) {
    __shared__ float Ws[32][33];
    __shared__ float Xs[64][33];
    int t = threadIdx.x;
    for (int i = t; i < 1024; i += 256) Ws[i >> 5][i & 31] = W[i];
    int r = t >> 2, lane = t & 3;
    int node = blockIdx.x * 64 + r;
    bool alive = node < n;
    float dd = 0.f;
    if (alive) {
        float s[8] = {0, 0, 0, 0, 0, 0, 0, 0};
        gather32(starts, es, (const uint4*)g, node, lane, s);
        dd = dis[node];
#pragma unroll
        for (int i = 0; i < 8; ++i) Xs[r][lane * 8 + i] = dd * s[i];
    }
    __syncthreads();                       // covers Ws and Xs
    if (alive) {
        int c0 = lane * 8;
        float acc[8];
#pragma unroll
        for (int i = 0; i < 8; ++i) acc[i] = bias[c0 + i];
#pragma unroll 8
        for (int k = 0; k < 32; ++k) {
            float xv = Xs[r][k];
#pragma unroll
            for (int i = 0; i < 8; ++i) acc[i] += xv * Ws[k][c0 + i];
        }
        __half2 h0 = __floats2half2_rn(dd * fmaxf(acc[0], 0.f), dd * fmaxf(acc[1], 0.f));
        __half2 h1 = __floats2half2_rn(dd * fmaxf(acc[2], 0.f), dd * fmaxf(acc[3], 0.f));
        __half2 h2 = __floats2half2_rn(dd * fmaxf(acc[4], 0.f), dd * fmaxf(acc[5], 0.f));
        __half2 h3 = __floats2half2_rn(dd * fmaxf(acc[6], 0.f), dd * fmaxf(acc[7], 0.f));
        uint4 u;
        u.x = *(unsigned int*)&h0; u.y = *(unsigned int*)&h1;
        u.z = *(unsigned int*)&h2; u.w = *(unsigned int*)&h3;
        ((uint4*)gout)[(size_t)node * 4 + lane] = u;
    }
}

// ---- fused output layer: out = [agg(g) @ Wmu + bmu | agg(g) @ Wlv + blv] ---
__global__ __launch_bounds__(256)
void k_fused_final(const int* __restrict__ starts, const int* __restrict__ es,
                   const float* __restrict__ dis, const __half* __restrict__ g,
                   const float* __restrict__ Wmu, const float* __restrict__ Wlv,
                   const float* __restrict__ bmu, const float* __restrict__ blv,
                   float* __restrict__ out, int n) {
    __shared__ float Ws[32][66];           // [k][c], mu cols 0-31, lv cols 32-63
    __shared__ float Xs[64][33];
    int t = threadIdx.x;
    for (int i = t; i < 1024; i += 256) {
        Ws[i >> 5][i & 31]        = Wmu[i];
        Ws[i >> 5][32 + (i & 31)] = Wlv[i];
    }
    int r = t >> 2, lane = t & 3;
    int node = blockIdx.x * 64 + r;
    bool alive = node < n;
    if (alive) {
        float s[8] = {0, 0, 0, 0, 0, 0, 0, 0};
        gather32(starts, es, (const uint4*)g, node, lane, s);
        float dd = dis[node];
#pragma unroll
        for (int i = 0; i < 8; ++i) Xs[r][lane * 8 + i] = dd * s[i];
    }
    __syncthreads();
    if (alive) {
        int c0 = lane * 8;
        float am[8], al[8];
#pragma unroll
        for (int i = 0; i < 8; ++i) { am[i] = bmu[c0 + i]; al[i] = blv[c0 + i]; }
#pragma unroll 4
        for (int k = 0; k < 32; ++k) {
            float xv = Xs[r][k];
#pragma unroll
            for (int i = 0; i < 8; ++i) {
                am[i] += xv * Ws[k][c0 + i];
                al[i] += xv * Ws[k][32 + c0 + i];
            }
        }
        float4* om = (float4*)out + (size_t)node * 8 + lane * 2;
        om[0] = make_float4(am[0], am[1], am[2], am[3]);
        om[1] = make_float4(am[4], am[5], am[6], am[7]);
        float4* ol = (float4*)(out + (size_t)n * 32) + (size_t)node * 8 + lane * 2;
        ol[0] = make_float4(al[0], al[1], al[2], al[3]);
        ol[1] = make_float4(al[4], al[5], al[6], al[7]);
    }
}

// ---- launch ----------------------------------------------------------------

extern "C" void kernel_launch(void* const* d_in, const int* in_sizes, int n_in,
                              void* d_out, int out_size, void* d_ws, size_t ws_size,
                              hipStream_t stream) {
    const float* x   = (const float*)d_in[0];
    const int*   ei  = (const int*)d_in[1];
    const float* W1  = (const float*)d_in[2];
    const float* b1  = (const float*)d_in[3];
    const float* W2  = (const float*)d_in[4];
    const float* b2  = (const float*)d_in[5];
    const float* Wmu = (const float*)d_in[6];
    const float* bmu = (const float*)d_in[7];
    const float* Wlv = (const float*)d_in[8];
    const float* blv = (const float*)d_in[9];
    float* out = (float*)d_out;

    int n = in_sizes[0] / 32;   // 100000
    int E = in_sizes[1] / 2;    // 1600000
    const int* src = ei;
    const int* dst = ei + E;
    int nbuck = (n + BK - 1) >> BK_BITS;   // 196 (<= 256)

    // workspace layout (all segments 16B-aligned)
    int*    bcur   = (int*)d_ws;                      // 256
    int     npad   = (n + 4) & ~3;
    int*    starts = bcur + 256;                      // n+1 (padded)
    float*  dis    = (float*)(starts + npad);         // n
    int*    es     = (int*)(dis + n);                 // E
    __half* gA     = (__half*)(es + E);               // n*32 fp16
    __half* gB     = gA + (size_t)n * 32;             // n*32 fp16
    int*    ebuf   = (int*)(gB + (size_t)n * 32);     // 256*CAP ints (16.8 MB)

    int nblk  = (E + CHUNK - 1) / CHUNK;
    int agrid = (n + 63) / 64;

    // ---- edge preprocessing ----
    hipMemsetAsync(bcur, 0, 256 * sizeof(int), stream);
    k_bucket<<<nblk, 256, 0, stream>>>(src, dst, bcur, ebuf, E);
    k_finalize<<<nbuck, BK, 0, stream>>>(bcur, starts, dis, ebuf, es, x, gA, n, E);

    // ---- layer 1 (agg + gemm fused) ----
    k_fused16<<<agrid, 256, 0, stream>>>(starts, es, dis, gA, W1, b1, gB, n);
    // ---- layer 2 ----
    k_fused16<<<agrid, 256, 0, stream>>>(starts, es, dis, gB, W2, b2, gA, n);
    // ---- mu/logvar ----
    k_fused_final<<<agrid, 256, 0, stream>>>(starts, es, dis, gA, Wmu, Wlv, bmu, blv, out, n);
}